// Round 5
// baseline (224.595 us; speedup 1.0000x reference)
//
#include <hip/hip_runtime.h>
#include <math.h>

// Problem constants (match reference)
constexpr int B = 1024;
constexpr int S = 50;
constexpr int H = 64;
constexpr int V = 40000;

// Native 16B vector type: __builtin_nontemporal_store rejects HIP's float4
// class; it accepts ext_vector_type. Same global_store_dwordx4, nt policy.
typedef float floatx4 __attribute__((ext_vector_type(4)));

// ---------------------------------------------------------------------------
// One templated kernel, two dispatches:
//   FULL=false (probe): identical compute path, but NO zero-stores and NO
//     atomics — writes the 50 probs to workspace. Its runtime = C_core,
//     readable from the total-duration delta. Also warms L2 for the real run.
//   FULL=true: R3 structure with two fixes:
//     - NO min-occupancy launch bound (R3's (256,4) capped VGPR<=128 with a
//       64-reg ur[] array -> likely scratch spill; let VGPR float)
//     - zero-stores are NONTEMPORAL (nt policy: coherent, no L2 allocate) ->
//       avoids evicting the fill's dirty 0xAA lines = avoids 2x write traffic
// ---------------------------------------------------------------------------
template<bool FULL>
__global__ __launch_bounds__(256) void rrd_kernel(
    const float* __restrict__ am,    // [B,S,H]
    const float* __restrict__ lm,    // [B,H]
    const int*   __restrict__ items, // [B,S] int32
    const float* __restrict__ Wr,    // [H,H]
    const float* __restrict__ Ur,    // [H,H]
    const float* __restrict__ Vw,    // [H]
    const float* __restrict__ Vb,    // [1]
    float* __restrict__ out,         // [B,V]
    float* __restrict__ ws)          // probe target, [B,S]
{
    const int b    = blockIdx.x;
    const int tid  = threadIdx.x;
    const int lane = tid & 63;
    const int wave = tid >> 6;

    __shared__ float s_am[S * H];      // 12.8 KB, linear
    __shared__ float s_Ur[H * 65];     // pad 65: per-lane row reads conflict-free
    __shared__ float s_l[H];
    __shared__ float s_sc[S];

    // ---- stage am: 800 coalesced float4 ----
    {
        const float4* src = reinterpret_cast<const float4*>(am + (size_t)b * S * H);
        float4*       dst = reinterpret_cast<float4*>(s_am);
        #pragma unroll
        for (int i = tid; i < S * H / 4; i += 256) dst[i] = src[i];
    }
    // ---- stage Ur: coalesced float4 -> padded LDS ----
    {
        const float4* src = reinterpret_cast<const float4*>(Ur);
        #pragma unroll
        for (int i = tid; i < H * H / 4; i += 256) {
            float4 u = src[i];
            const int r = (4 * i) >> 6, c = (4 * i) & 63;
            float* d = &s_Ur[r * 65 + c];
            d[0] = u.x; d[1] = u.y; d[2] = u.z; d[3] = u.w;
        }
    }
    // ---- l[k] = <lm[b,:], Wr[k,:]> (one wave; Wr 16 KB, L2-hot) ----
    if (tid < H) {
        const float4* w4 = reinterpret_cast<const float4*>(Wr + tid * H);
        const float4* l4 = reinterpret_cast<const float4*>(lm + (size_t)b * H);
        float acc = 0.f;
        #pragma unroll
        for (int i = 0; i < H / 4; ++i) {
            float4 w = w4[i], x = l4[i];
            acc = fmaf(x.x, w.x, acc); acc = fmaf(x.y, w.y, acc);
            acc = fmaf(x.z, w.z, acc); acc = fmaf(x.w, w.w, acc);
        }
        s_l[tid] = acc;
    }
    const int   my_item = (tid < S) ? items[b * S + tid] : 0;
    const float vb      = Vb[0];
    const float vw      = Vw[lane];
    __syncthreads();   // barrier 1 (no stores issued yet -> cheap drain)

    // ---- zero-stores (FULL only): nontemporal, issued after barrier 1 so
    //      they drain under the score loop and only block at barrier 2 ----
    if (FULL) {
        floatx4* row4 = reinterpret_cast<floatx4*>(out + (size_t)b * V);
        const floatx4 z = {0.f, 0.f, 0.f, 0.f};
        #pragma unroll 10
        for (int i = tid; i < V / 4; i += 256)
            __builtin_nontemporal_store(z, &row4[i]);
    }

    // ---- per-lane Ur row from LDS (stride 65 -> conflict-free) ----
    float ur[H];
    #pragma unroll
    for (int h = 0; h < H; ++h) ur[h] = s_Ur[lane * 65 + h];
    const float lk = s_l[lane];

    // ---- scores: wave w handles s = w, w+4, ... ----
    for (int s = wave; s < S; s += 4) {
        const float4* a4 = reinterpret_cast<const float4*>(s_am + s * H);
        float acc = lk;
        #pragma unroll
        for (int i = 0; i < H / 4; ++i) {
            float4 v = a4[i];
            acc = fmaf(v.x, ur[4 * i + 0], acc);
            acc = fmaf(v.y, ur[4 * i + 1], acc);
            acc = fmaf(v.z, ur[4 * i + 2], acc);
            acc = fmaf(v.w, ur[4 * i + 3], acc);
        }
        float t = tanhf(acc) * vw;
        #pragma unroll
        for (int off = 32; off; off >>= 1) t += __shfl_xor(t, off, 64);
        if (lane == 0) s_sc[s] = t + vb;
    }
    __syncthreads();   // barrier 2: s_sc visible; drains zero-stores (FULL)

    // ---- softmax over S=50 + emit (wave 0, registers only) ----
    if (wave == 0) {
        float x = (lane < S) ? s_sc[lane] : -INFINITY;
        float m = x;
        #pragma unroll
        for (int off = 32; off; off >>= 1) m = fmaxf(m, __shfl_xor(m, off, 64));
        float e = (lane < S) ? expf(x - m) : 0.f;
        float sum = e;
        #pragma unroll
        for (int off = 32; off; off >>= 1) sum += __shfl_xor(sum, off, 64);
        if (lane < S) {
            if (FULL) {
                atomicAdd(out + (size_t)b * V + my_item, e / sum);  // dups accumulate
            } else {
                ws[b * S + lane] = e / sum;   // probe: linear write, no atomics
            }
        }
    }
}

extern "C" void kernel_launch(void* const* d_in, const int* in_sizes, int n_in,
                              void* d_out, int out_size, void* d_ws, size_t ws_size,
                              hipStream_t stream) {
    const float* am    = (const float*)d_in[0];  // all_memory [B,S,H]
    const float* lm    = (const float*)d_in[1];  // last_memory [B,H]
    const int*   items = (const int*)  d_in[2];  // seq_item [B,S]
    const float* Wr    = (const float*)d_in[3];  // [H,H]
    const float* Ur    = (const float*)d_in[4];  // [H,H]
    const float* Vw    = (const float*)d_in[5];  // [H]
    const float* Vb    = (const float*)d_in[6];  // scalar
    float* out = (float*)d_out;                  // [B,V] fp32
    float* ws  = (float*)d_ws;

    // Timing probe: identical compute path, no stores/atomics, probs -> ws.
    // Cost of this dispatch == C_core (read off the total-duration delta).
    if (ws_size >= (size_t)B * S * sizeof(float)) {
        rrd_kernel<false><<<dim3(B), dim3(256), 0, stream>>>(
            am, lm, items, Wr, Ur, Vw, Vb, out, ws);
    }

    rrd_kernel<true><<<dim3(B), dim3(256), 0, stream>>>(
        am, lm, items, Wr, Ur, Vw, Vb, out, ws);
}

// Round 6
// 195.233 us; speedup vs baseline: 1.1504x; 1.1504x over previous
//
#include <hip/hip_runtime.h>
#include <math.h>

// Problem constants (match reference)
constexpr int B = 1024;
constexpr int S = 50;
constexpr int H = 64;
constexpr int V = 40000;

// ---------------------------------------------------------------------------
// Final decomposition (each half separately measured across R0-R5):
//   1) hipMemsetAsync zeroes out[B*V]   -- runtime fill path, ~25 us @6.5TB/s
//      (in-kernel store bursts measured ~2 TB/s; dedicated kernel 4.3 TB/s;
//       memset is the only path that matches fillBufferAligned's rate)
//   2) compute kernel (R3/R5-probe structure, measured ~15-20 us):
//      - am staged as 800 coalesced float4 into linear LDS
//      - Ur staged cooperatively into pad-65 LDS -> per-lane row reads
//        conflict-free (per-lane GLOBAL row reads were R2's 86us pathology:
//        64 distinct cache lines per load instruction)
//      - l[k] by one wave, broadcast via LDS
//      - scores: wave w owns s = w, w+4, ...; shfl-xor butterfly k-reduce
//      - softmax + atomic scatter in wave 0 registers (dups accumulate)
//      - no zero-stores, no probe dispatch
// ---------------------------------------------------------------------------
__global__ __launch_bounds__(256) void rrd_compute(
    const float* __restrict__ am,    // [B,S,H]
    const float* __restrict__ lm,    // [B,H]
    const int*   __restrict__ items, // [B,S] int32
    const float* __restrict__ Wr,    // [H,H]
    const float* __restrict__ Ur,    // [H,H]
    const float* __restrict__ Vw,    // [H]
    const float* __restrict__ Vb,    // [1]
    float* __restrict__ out)         // [B,V], zeroed by memset
{
    const int b    = blockIdx.x;
    const int tid  = threadIdx.x;
    const int lane = tid & 63;
    const int wave = tid >> 6;

    __shared__ float s_am[S * H];      // 12.8 KB, linear
    __shared__ float s_Ur[H * 65];     // pad 65: per-lane row reads conflict-free
    __shared__ float s_l[H];
    __shared__ float s_sc[S];

    // ---- stage am: 800 coalesced float4 ----
    {
        const float4* src = reinterpret_cast<const float4*>(am + (size_t)b * S * H);
        float4*       dst = reinterpret_cast<float4*>(s_am);
        #pragma unroll
        for (int i = tid; i < S * H / 4; i += 256) dst[i] = src[i];
    }
    // ---- stage Ur: coalesced float4 -> padded LDS ----
    {
        const float4* src = reinterpret_cast<const float4*>(Ur);
        #pragma unroll
        for (int i = tid; i < H * H / 4; i += 256) {
            float4 u = src[i];
            const int r = (4 * i) >> 6, c = (4 * i) & 63;
            float* d = &s_Ur[r * 65 + c];
            d[0] = u.x; d[1] = u.y; d[2] = u.z; d[3] = u.w;
        }
    }
    // ---- l[k] = <lm[b,:], Wr[k,:]> (one wave; Wr 16 KB, L2-hot) ----
    if (tid < H) {
        const float4* w4 = reinterpret_cast<const float4*>(Wr + tid * H);
        const float4* l4 = reinterpret_cast<const float4*>(lm + (size_t)b * H);
        float acc = 0.f;
        #pragma unroll
        for (int i = 0; i < H / 4; ++i) {
            float4 w = w4[i], x = l4[i];
            acc = fmaf(x.x, w.x, acc); acc = fmaf(x.y, w.y, acc);
            acc = fmaf(x.z, w.z, acc); acc = fmaf(x.w, w.w, acc);
        }
        s_l[tid] = acc;
    }
    const int   my_item = (tid < S) ? items[b * S + tid] : 0;  // prefetch
    const float vb      = Vb[0];
    const float vw      = Vw[lane];
    __syncthreads();   // barrier 1: staging + s_l visible

    // ---- per-lane Ur row from LDS (stride 65 -> conflict-free) ----
    float ur[H];
    #pragma unroll
    for (int h = 0; h < H; ++h) ur[h] = s_Ur[lane * 65 + h];
    const float lk = s_l[lane];

    // ---- scores: wave w handles s = w, w+4, ... (broadcast LDS reads) ----
    for (int s = wave; s < S; s += 4) {
        const float4* a4 = reinterpret_cast<const float4*>(s_am + s * H);
        float acc = lk;
        #pragma unroll
        for (int i = 0; i < H / 4; ++i) {
            float4 v = a4[i];
            acc = fmaf(v.x, ur[4 * i + 0], acc);
            acc = fmaf(v.y, ur[4 * i + 1], acc);
            acc = fmaf(v.z, ur[4 * i + 2], acc);
            acc = fmaf(v.w, ur[4 * i + 3], acc);
        }
        float t = tanhf(acc) * vw;
        #pragma unroll
        for (int off = 32; off; off >>= 1) t += __shfl_xor(t, off, 64);
        if (lane == 0) s_sc[s] = t + vb;
    }
    __syncthreads();   // barrier 2: s_sc visible to wave 0

    // ---- softmax over S=50 + scatter (wave 0, registers only) ----
    if (wave == 0) {
        float x = (lane < S) ? s_sc[lane] : -INFINITY;
        float m = x;
        #pragma unroll
        for (int off = 32; off; off >>= 1) m = fmaxf(m, __shfl_xor(m, off, 64));
        float e = (lane < S) ? expf(x - m) : 0.f;
        float sum = e;
        #pragma unroll
        for (int off = 32; off; off >>= 1) sum += __shfl_xor(sum, off, 64);
        if (lane < S)
            atomicAdd(out + (size_t)b * V + my_item, e / sum);  // dups accumulate
    }
}

extern "C" void kernel_launch(void* const* d_in, const int* in_sizes, int n_in,
                              void* d_out, int out_size, void* d_ws, size_t ws_size,
                              hipStream_t stream) {
    const float* am    = (const float*)d_in[0];  // all_memory [B,S,H]
    const float* lm    = (const float*)d_in[1];  // last_memory [B,H]
    const int*   items = (const int*)  d_in[2];  // seq_item [B,S]
    const float* Wr    = (const float*)d_in[3];  // [H,H]
    const float* Ur    = (const float*)d_in[4];  // [H,H]
    const float* Vw    = (const float*)d_in[5];  // [H]
    const float* Vb    = (const float*)d_in[6];  // scalar
    float* out = (float*)d_out;                  // [B,V] fp32

    // Zero via the runtime fill path: ~25 us @ 6.5 TB/s (measured R2).
    // Graph-capture-safe (the harness's own reset() enqueues hipMemsetAsync).
    hipMemsetAsync(d_out, 0, (size_t)B * V * sizeof(float), stream);

    rrd_compute<<<dim3(B), dim3(256), 0, stream>>>(
        am, lm, items, Wr, Ur, Vw, Vb, out);
}